// Round 1
// baseline (154130.603 us; speedup 1.0000x reference)
//
#include <hip/hip_runtime.h>
#include <hip/hip_cooperative_groups.h>

namespace cg = cooperative_groups;

constexpr int NSTATE = 4096;
constexpr int NOBS   = 128;
constexpr int TSEQ   = 1024;
constexpr int NWG    = 256;   // one workgroup per CU
constexpr int NTHR   = 1024;  // 16 waves

// workspace layout (float slots)
constexpr int WS_BT  = 0;                   // Bt[128][4096]
constexpr int WS_OBS = NOBS * NSTATE;       // obs as int[1024]
constexpr int WS_Y2  = WS_OBS + TSEQ;       // y2[2][2][4096]
// total ~2.07 MiB

__global__ __launch_bounds__(NTHR) void hmm_fwd_kernel(
    const float* __restrict__ A,
    const float* __restrict__ B,
    const float* __restrict__ pi,
    const void*  __restrict__ obs_raw,
    float* __restrict__ out,
    float* __restrict__ ws)
{
  cg::grid_group grid = cg::this_grid();
  const int tid = threadIdx.x;
  const int w   = blockIdx.x;

  float* __restrict__ Bt   = ws + WS_BT;
  int*   __restrict__ obsg = (int*)(ws + WS_OBS);
  float* __restrict__ y2   = ws + WS_Y2;   // [buf][half][4096]

  __shared__ float x_lds[NSTATE];      // 16 KiB: current alpha (full copy per wg)
  __shared__ float red_f[512];         // 2 KiB: [wave][c4] float4 partials
  __shared__ int   obs_lds[TSEQ];      // 4 KiB
  __shared__ int   flag_lds;
  __shared__ float fin[16];

  // ---------- pre-phase: transpose B -> Bt, decode obs (int32 vs int64) ----------
  for (int e = w * NTHR + tid; e < NOBS * NSTATE; e += NWG * NTHR) {
    const int o = e >> 12;            // / 4096
    const int j = e & (NSTATE - 1);
    Bt[(size_t)o * NSTATE + j] = B[(size_t)j * NOBS + o];
  }
  if (w == 0) {
    if (tid == 0) flag_lds = 0;
    __syncthreads();
    const long long* p64 = (const long long*)obs_raw;
    if (tid < 256) {                  // safe window under either layout
      const long long v = p64[tid];
      if (v < 0 || v >= NOBS) atomicOr(&flag_lds, 1);
    }
    __syncthreads();
    const bool is32 = (flag_lds != 0);
    const int* p32 = (const int*)obs_raw;
    obsg[tid] = is32 ? p32[tid] : (int)p64[tid];
  }
  __threadfence();
  grid.sync();
  __threadfence();

  // obs to LDS; init x = alpha0 = pi * Bt[obs[0]]
  obs_lds[tid] = obsg[tid];
  __syncthreads();
  {
    const int o0 = obs_lds[0];
    const float4 p = ((const float4*)pi)[tid];
    const float4 b = ((const float4*)(Bt + ((size_t)o0 << 12)))[tid];
    float4 x;
    x.x = p.x * b.x; x.y = p.y * b.y; x.z = p.z * b.z; x.w = p.w * b.w;
    ((float4*)x_lds)[tid] = x;
  }
  __syncthreads();

  // ---------- main recursion ----------
  const int chunk   = w >> 1;           // 0..127: 32-column chunk
  const int half    = w & 1;            // row half
  const int colbase = chunk << 5;
  const int c4   = tid & 7;             // 4-column subgroup within chunk
  const int rg   = tid >> 3;            // 0..127 row-group
  const int col0 = colbase + (c4 << 2);
  const int wave = tid >> 6;
  const int lane = tid & 63;
  const int ibase = (half << 11) + (rg << 4);  // 16 rows per thread

  const float* __restrict__ Abase = A + (size_t)ibase * NSTATE + col0;

  for (int t = 1; t < TSEQ; ++t) {
    // grab this thread's 16 x values from LDS (4x ds_read_b128)
    float xr[16];
    {
      const float4* xl = (const float4*)(x_lds + ibase);
#pragma unroll
      for (int q = 0; q < 4; ++q) {
        const float4 v = xl[q];
        xr[4*q+0] = v.x; xr[4*q+1] = v.y; xr[4*q+2] = v.z; xr[4*q+3] = v.w;
      }
    }
    // partial dot-products: 16 rows x 4 cols (each wave reads 8 full 128B lines/instr)
    float ax = 0.f, ay = 0.f, az = 0.f, aw = 0.f;
#pragma unroll
    for (int k = 0; k < 16; ++k) {
      const float4 a = *(const float4*)(Abase + (size_t)k * NSTATE);
      ax = fmaf(xr[k], a.x, ax);
      ay = fmaf(xr[k], a.y, ay);
      az = fmaf(xr[k], a.z, az);
      aw = fmaf(xr[k], a.w, aw);
    }
    // reduce over the 8 row-groups inside each wave (lane bits 3..5)
#pragma unroll
    for (int m = 8; m <= 32; m <<= 1) {
      ax += __shfl_xor(ax, m);
      ay += __shfl_xor(ay, m);
      az += __shfl_xor(az, m);
      aw += __shfl_xor(aw, m);
    }
    if ((lane >> 3) == 0) {
      ((float4*)red_f)[(wave << 3) + c4] = make_float4(ax, ay, az, aw);
    }
    __syncthreads();
    const int buf = t & 1;
    if (tid < 32) {  // one thread per owned column: combine 16 wave partials
      float s = 0.f;
      const int cgrp = tid >> 2, ce = tid & 3;
#pragma unroll
      for (int wv = 0; wv < 16; ++wv) {
        s += red_f[(((wv << 3) + cgrp) << 2) + ce];
      }
      y2[(size_t)((buf << 1) + half) * NSTATE + colbase + tid] = s;
    }
    __threadfence();      // release y2 stores (cross-XCD)
    grid.sync();
    __threadfence();      // acquire (invalidate stale L1/L2 copies)
    // stage next alpha: x = (y_half0 + y_half1) * Bt[obs[t]]
    {
      const int o = obs_lds[t];
      const float4 a0 = ((const float4*)(y2 + (size_t)((buf << 1) + 0) * NSTATE))[tid];
      const float4 a1 = ((const float4*)(y2 + (size_t)((buf << 1) + 1) * NSTATE))[tid];
      const float4 bb = ((const float4*)(Bt + ((size_t)o << 12)))[tid];
      float4 xx;
      xx.x = (a0.x + a1.x) * bb.x;
      xx.y = (a0.y + a1.y) * bb.y;
      xx.z = (a0.z + a1.z) * bb.z;
      xx.w = (a0.w + a1.w) * bb.w;
      ((float4*)x_lds)[tid] = xx;
    }
    __syncthreads();
  }

  // ---------- final sum over alpha (x_lds is complete in every wg) ----------
  if (w == 0) {
    const float4 v = ((const float4*)x_lds)[tid];
    float s = v.x + v.y + v.z + v.w;
#pragma unroll
    for (int m = 1; m <= 32; m <<= 1) s += __shfl_xor(s, m);
    if (lane == 0) fin[wave] = s;
    __syncthreads();
    if (tid == 0) {
      float tot = 0.f;
#pragma unroll
      for (int i = 0; i < 16; ++i) tot += fin[i];
      out[0] = tot;
    }
  }
}

extern "C" void kernel_launch(void* const* d_in, const int* in_sizes, int n_in,
                              void* d_out, int out_size, void* d_ws, size_t ws_size,
                              hipStream_t stream) {
  const float* A   = (const float*)d_in[0];
  const float* B   = (const float*)d_in[1];
  const float* pi  = (const float*)d_in[2];
  const void*  obs = d_in[3];
  float* out = (float*)d_out;
  float* ws  = (float*)d_ws;

  void* args[] = { &A, &B, &pi, &obs, &out, &ws };
  hipLaunchCooperativeKernel((void*)hmm_fwd_kernel, dim3(NWG), dim3(NTHR),
                             args, 0, stream);
}

// Round 3
// 6473.907 us; speedup vs baseline: 23.8080x; 23.8080x over previous
//
#include <hip/hip_runtime.h>

constexpr int NSTATE = 4096;
constexpr int NOBS   = 128;
constexpr int TSEQ   = 1024;
constexpr int NWG    = 256;   // one workgroup per CU (cooperative: co-resident)
constexpr int NTHR   = 1024;  // 16 waves

// workspace layout (float slots)
constexpr size_t WS_BT    = 0;                        // Bt[128][4096]
constexpr size_t WS_OBS   = (size_t)NOBS * NSTATE;    // obs as int[1024]
constexpr size_t WS_Y2    = WS_OBS + TSEQ;            // y2[2][2][4096]
constexpr size_t WS_FLAGS = WS_Y2 + 4 * NSTATE;       // int flags[256] (128B-aligned)

__device__ __forceinline__ int agent_ld_i32(const int* p) {
  return __hip_atomic_load(p, __ATOMIC_RELAXED, __HIP_MEMORY_SCOPE_AGENT);
}
__device__ __forceinline__ void agent_st_i32(int* p, int v) {
  __hip_atomic_store(p, v, __ATOMIC_RELAXED, __HIP_MEMORY_SCOPE_AGENT);
}
__device__ __forceinline__ void agent_st_f32(float* p, float v) {
  __hip_atomic_store(p, v, __ATOMIC_RELAXED, __HIP_MEMORY_SCOPE_AGENT);
}
__device__ __forceinline__ unsigned long long agent_ld_u64(const unsigned long long* p) {
  return __hip_atomic_load(p, __ATOMIC_RELAXED, __HIP_MEMORY_SCOPE_AGENT);
}

// Flag barrier: no RMW, no cache-wide fences. Epochs are strictly increasing,
// so no reset is needed; 0xAA poison is negative as int -> can't false-pass.
// Caller guarantees all prior cross-wg data was written with agent-scope
// (write-through) stores; the vmcnt(0) wait orders them before the flag store.
__device__ __forceinline__ void grid_bar(int* flags, int w, int tid, int epoch) {
  asm volatile("s_waitcnt vmcnt(0)" ::: "memory");
  __syncthreads();                 // all waves' stores issued before flag
  if (tid == 0) agent_st_i32(&flags[w], epoch);
  if (tid < 64) {                  // wave 0 polls: 4 flags per lane, coalesced
    for (;;) {
      int m0 = agent_ld_i32(&flags[tid]);
      int m1 = agent_ld_i32(&flags[tid + 64]);
      int m2 = agent_ld_i32(&flags[tid + 128]);
      int m3 = agent_ld_i32(&flags[tid + 192]);
      int mn = min(min(m0, m1), min(m2, m3));
      if (__all(mn >= epoch)) break;
    }
  }
  __syncthreads();
}

__global__ __launch_bounds__(NTHR) void hmm_fwd_kernel(
    const float* __restrict__ A,
    const float* __restrict__ B,
    const float* __restrict__ pi,
    const void*  __restrict__ obs_raw,
    float* __restrict__ out,
    float* __restrict__ ws)
{
  const int tid = threadIdx.x;
  const int w   = blockIdx.x;

  float* __restrict__ Bt   = ws + WS_BT;
  int*   __restrict__ obsg = (int*)(ws + WS_OBS);
  float* __restrict__ y2   = ws + WS_Y2;     // [buf][half][4096]
  int*   __restrict__ flags = (int*)(ws + WS_FLAGS);

  __shared__ float x_lds[NSTATE];    // 16 KiB: current alpha (full copy per wg)
  __shared__ float red_f[512];       // [wave][c4] float4 partials
  __shared__ int   obs_lds[TSEQ];
  __shared__ int   flag_lds;
  __shared__ float fin[16];

  // ---- static work assignment ----
  const int chunk   = w >> 1;            // 0..127: 32-column chunk
  const int half    = w & 1;             // row half
  const int colbase = chunk << 5;
  const int c4   = tid & 7;              // 4-column subgroup
  const int rg   = tid >> 3;             // 0..127 row-group
  const int col0 = colbase + (c4 << 2);
  const int wave = tid >> 6;
  const int lane = tid & 63;
  const int ibase = (half << 11) + (rg << 4);   // 16 rows per thread

  // ---- preload this thread's fixed 16x4 A-block into registers (64 VGPR) ----
  const float* __restrict__ Abase = A + (size_t)ibase * NSTATE + col0;
  float4 areg[16];
#pragma unroll
  for (int k = 0; k < 16; ++k)
    areg[k] = *(const float4*)(Abase + (size_t)k * NSTATE);

  // ---- pre-phase: transpose B -> Bt (write-through), decode obs ----
  for (int e = w * NTHR + tid; e < NOBS * NSTATE; e += NWG * NTHR) {
    const int o = e >> 12;
    const int j = e & (NSTATE - 1);
    agent_st_f32(&Bt[(size_t)o * NSTATE + j], B[(size_t)j * NOBS + o]);
  }
  if (w == 0) {
    if (tid == 0) flag_lds = 0;
    __syncthreads();
    const long long* p64 = (const long long*)obs_raw;
    if (tid < 256) {                    // probe window valid under either layout
      const long long v = p64[tid];
      if (v < 0 || v >= NOBS) atomicOr(&flag_lds, 1);
    }
    __syncthreads();
    const bool is32 = (flag_lds != 0);
    const int* p32 = (const int*)obs_raw;
    agent_st_i32(&obsg[tid], is32 ? p32[tid] : (int)p64[tid]);
  }
  grid_bar(flags, w, tid, 1);

  // obs -> LDS; init x = alpha0 = pi * Bt[obs[0]]
  obs_lds[tid] = obsg[tid];   // first touch on this XCD; source was write-through
  __syncthreads();
  {
    const int o0 = obs_lds[0];
    const float4 p = ((const float4*)pi)[tid];
    const float4 b = ((const float4*)(Bt + ((size_t)o0 << 12)))[tid];
    float4 x;
    x.x = p.x * b.x; x.y = p.y * b.y; x.z = p.z * b.z; x.w = p.w * b.w;
    ((float4*)x_lds)[tid] = x;
  }
  __syncthreads();

  // ---- main recursion: one flag-barrier per step ----
  for (int t = 1; t < TSEQ; ++t) {
    // x fragment from LDS
    float xr[16];
    {
      const float4* xl = (const float4*)(x_lds + ibase);
#pragma unroll
      for (int q = 0; q < 4; ++q) {
        const float4 v = xl[q];
        xr[4*q+0] = v.x; xr[4*q+1] = v.y; xr[4*q+2] = v.z; xr[4*q+3] = v.w;
      }
    }
    // partial dots from register-resident A
    float ax = 0.f, ay = 0.f, az = 0.f, aw = 0.f;
#pragma unroll
    for (int k = 0; k < 16; ++k) {
      ax = fmaf(xr[k], areg[k].x, ax);
      ay = fmaf(xr[k], areg[k].y, ay);
      az = fmaf(xr[k], areg[k].z, az);
      aw = fmaf(xr[k], areg[k].w, aw);
    }
    // reduce the 8 row-groups within each wave (lane bits 3..5)
#pragma unroll
    for (int m = 8; m <= 32; m <<= 1) {
      ax += __shfl_xor(ax, m);
      ay += __shfl_xor(ay, m);
      az += __shfl_xor(az, m);
      aw += __shfl_xor(aw, m);
    }
    if ((lane >> 3) == 0) {
      ((float4*)red_f)[(wave << 3) + c4] = make_float4(ax, ay, az, aw);
    }
    __syncthreads();
    const int buf = t & 1;
    if (tid < 32) {   // combine 16 wave partials -> y2 (write-through)
      float s = 0.f;
      const int cgrp = tid >> 2, ce = tid & 3;
#pragma unroll
      for (int wv = 0; wv < 16; ++wv) {
        s += red_f[(((wv << 3) + cgrp) << 2) + ce];
      }
      agent_st_f32(&y2[(size_t)((buf << 1) + half) * NSTATE + colbase + tid], s);
    }
    grid_bar(flags, w, tid, t + 1);
    // stage next alpha: x = (y_half0 + y_half1) * Bt[obs[t]]  (bypassing loads)
    {
      const int o = obs_lds[t];
      const unsigned long long* yA =
          (const unsigned long long*)(y2 + (size_t)(buf << 1) * NSTATE);
      const unsigned long long* yB = yA + (NSTATE / 2);
      unsigned long long a0 = agent_ld_u64(&yA[2 * tid]);
      unsigned long long a1 = agent_ld_u64(&yA[2 * tid + 1]);
      unsigned long long b0 = agent_ld_u64(&yB[2 * tid]);
      unsigned long long b1 = agent_ld_u64(&yB[2 * tid + 1]);
      const float4 bb = ((const float4*)(Bt + ((size_t)o << 12)))[tid];
      union U { unsigned long long u; float2 f; };
      U ua0, ua1, ub0, ub1;
      ua0.u = a0; ua1.u = a1; ub0.u = b0; ub1.u = b1;
      float4 xx;
      xx.x = (ua0.f.x + ub0.f.x) * bb.x;
      xx.y = (ua0.f.y + ub0.f.y) * bb.y;
      xx.z = (ua1.f.x + ub1.f.x) * bb.z;
      xx.w = (ua1.f.y + ub1.f.y) * bb.w;
      ((float4*)x_lds)[tid] = xx;
    }
    __syncthreads();
  }

  // ---- final sum over alpha (x_lds complete in every wg; wg 0 reports) ----
  if (w == 0) {
    const float4 v = ((const float4*)x_lds)[tid];
    float s = v.x + v.y + v.z + v.w;
#pragma unroll
    for (int m = 1; m <= 32; m <<= 1) s += __shfl_xor(s, m);
    if (lane == 0) fin[wave] = s;
    __syncthreads();
    if (tid == 0) {
      float tot = 0.f;
#pragma unroll
      for (int i = 0; i < 16; ++i) tot += fin[i];
      out[0] = tot;
    }
  }
}

extern "C" void kernel_launch(void* const* d_in, const int* in_sizes, int n_in,
                              void* d_out, int out_size, void* d_ws, size_t ws_size,
                              hipStream_t stream) {
  const float* A   = (const float*)d_in[0];
  const float* B   = (const float*)d_in[1];
  const float* pi  = (const float*)d_in[2];
  const void*  obs = d_in[3];
  float* out = (float*)d_out;
  float* ws  = (float*)d_ws;

  void* args[] = { &A, &B, &pi, &obs, &out, &ws };
  hipLaunchCooperativeKernel((void*)hmm_fwd_kernel, dim3(NWG), dim3(NTHR),
                             args, 0, stream);
}

// Round 4
// 6090.247 us; speedup vs baseline: 25.3078x; 1.0630x over previous
//
#include <hip/hip_runtime.h>

constexpr int NSTATE = 4096;
constexpr int NOBS   = 128;
constexpr int TSEQ   = 1024;
constexpr int NWG    = 256;   // one workgroup per CU (cooperative: co-resident)
constexpr int NTHR   = 1024;  // 16 waves

// workspace layout (float slots)
constexpr size_t WS_BT    = 0;                        // Bt[128][4096]
constexpr size_t WS_OBS   = (size_t)NOBS * NSTATE;    // obs as int[1024]
constexpr size_t WS_Y2    = WS_OBS + TSEQ;            // y2[2][2][4096]
constexpr size_t WS_FLAGS = WS_Y2 + 4 * NSTATE;       // int flags[256]

__device__ __forceinline__ int agent_ld_i32(const int* p) {
  return __hip_atomic_load(p, __ATOMIC_RELAXED, __HIP_MEMORY_SCOPE_AGENT);
}
__device__ __forceinline__ void agent_st_i32(int* p, int v) {
  __hip_atomic_store(p, v, __ATOMIC_RELAXED, __HIP_MEMORY_SCOPE_AGENT);
}
__device__ __forceinline__ void agent_st_f32(float* p, float v) {
  __hip_atomic_store(p, v, __ATOMIC_RELAXED, __HIP_MEMORY_SCOPE_AGENT);
}
__device__ __forceinline__ unsigned long long agent_ld_u64(const unsigned long long* p) {
  return __hip_atomic_load(p, __ATOMIC_RELAXED, __HIP_MEMORY_SCOPE_AGENT);
}

// Pre-loop barrier: every wave may have outstanding agent stores (Bt transpose),
// so each wave drains vmcnt before the leader signals.
__device__ __forceinline__ void grid_bar_full(int* flags, int w, int tid, int epoch) {
  asm volatile("s_waitcnt vmcnt(0)" ::: "memory");
  __syncthreads();
  if (tid == 0) agent_st_i32(&flags[w], epoch);
  if (tid < 64) {
    for (;;) {
      int m0 = agent_ld_i32(&flags[tid]);
      int m1 = agent_ld_i32(&flags[tid + 64]);
      int m2 = agent_ld_i32(&flags[tid + 128]);
      int m3 = agent_ld_i32(&flags[tid + 192]);
      int mn = min(min(m0, m1), min(m2, m3));
      if (__all(mn >= epoch)) break;
    }
  }
  __syncthreads();
}

// In-loop barrier: y2 is produced ONLY by wave 0 (tid<32) after a preceding
// __syncthreads, so only wave 0 needs vmcnt(0) before the flag store. Other
// waves go straight to the closing __syncthreads. Epochs are monotone ->
// no flag reset; 0xAA poison is negative as int -> can't false-pass.
__device__ __forceinline__ void grid_bar_fast(int* flags, int w, int tid, int epoch) {
  if (tid < 64) {
    asm volatile("s_waitcnt vmcnt(0)" ::: "memory");
    if (tid == 0) agent_st_i32(&flags[w], epoch);
    for (;;) {
      int m0 = agent_ld_i32(&flags[tid]);
      int m1 = agent_ld_i32(&flags[tid + 64]);
      int m2 = agent_ld_i32(&flags[tid + 128]);
      int m3 = agent_ld_i32(&flags[tid + 192]);
      int mn = min(min(m0, m1), min(m2, m3));
      if (__all(mn >= epoch)) break;
    }
  }
  __syncthreads();
}

__global__ __launch_bounds__(NTHR) void hmm_fwd_kernel(
    const float* __restrict__ A,
    const float* __restrict__ B,
    const float* __restrict__ pi,
    const void*  __restrict__ obs_raw,
    float* __restrict__ out,
    float* __restrict__ ws)
{
  const int tid = threadIdx.x;
  const int w   = blockIdx.x;

  float* __restrict__ Bt    = ws + WS_BT;
  int*   __restrict__ obsg  = (int*)(ws + WS_OBS);
  float* __restrict__ y2    = ws + WS_Y2;     // [buf][half][4096]
  int*   __restrict__ flags = (int*)(ws + WS_FLAGS);

  __shared__ float x_lds[NSTATE];    // current alpha (full copy per wg)
  __shared__ float red_f[512];       // [wave][c4] float4 partials
  __shared__ int   obs_lds[TSEQ];
  __shared__ int   flag_lds;
  __shared__ float fin[16];

  // ---- static work assignment ----
  const int chunk   = w >> 1;            // 0..127: 32-column chunk
  const int half    = w & 1;             // row half
  const int colbase = chunk << 5;
  const int c4   = tid & 7;              // 4-column subgroup
  const int rg   = tid >> 3;             // 0..127 row-group
  const int col0 = colbase + (c4 << 2);
  const int wave = tid >> 6;
  const int lane = tid & 63;
  const int ibase = (half << 11) + (rg << 4);   // 16 rows per thread

  // ---- preload this thread's fixed 16x4 A-block into 64 PINNED registers ----
  const float* __restrict__ Abase = A + (size_t)ibase * NSTATE + col0;
  float ar[64];
#pragma unroll
  for (int k = 0; k < 16; ++k) {
    const float4 v = *(const float4*)(Abase + (size_t)k * NSTATE);
    ar[4*k+0] = v.x; ar[4*k+1] = v.y; ar[4*k+2] = v.z; ar[4*k+3] = v.w;
  }
  // Opaque-define each value: the barrier's "memory" clobber can no longer
  // cause the compiler to re-load A inside the t-loop (R3: VGPR=52 proved it did).
#pragma unroll
  for (int i = 0; i < 64; ++i) asm volatile("" : "+v"(ar[i]));

  // ---- pre-phase: transpose B -> Bt (agent stores), decode obs ----
  for (int e = w * NTHR + tid; e < NOBS * NSTATE; e += NWG * NTHR) {
    const int o = e >> 12;
    const int j = e & (NSTATE - 1);
    agent_st_f32(&Bt[(size_t)o * NSTATE + j], B[(size_t)j * NOBS + o]);
  }
  if (w == 0) {
    if (tid == 0) flag_lds = 0;
    __syncthreads();
    const long long* p64 = (const long long*)obs_raw;
    if (tid < 256) {                    // probe window valid under either layout
      const long long v = p64[tid];
      if (v < 0 || v >= NOBS) atomicOr(&flag_lds, 1);
    }
    __syncthreads();
    const bool is32 = (flag_lds != 0);
    const int* p32 = (const int*)obs_raw;
    agent_st_i32(&obsg[tid], is32 ? p32[tid] : (int)p64[tid]);
  }
  grid_bar_full(flags, w, tid, 1);

  // obs -> LDS; init x = alpha0 = pi * Bt[obs[0]]
  obs_lds[tid] = obsg[tid];
  __syncthreads();
  {
    const int o0 = obs_lds[0];
    const float4 p = ((const float4*)pi)[tid];
    const float4 b = ((const float4*)(Bt + ((size_t)o0 << 12)))[tid];
    float4 x;
    x.x = p.x * b.x; x.y = p.y * b.y; x.z = p.z * b.z; x.w = p.w * b.w;
    ((float4*)x_lds)[tid] = x;
  }
  __syncthreads();

  // ---- main recursion: one flag-barrier per step ----
  for (int t = 1; t < TSEQ; ++t) {
    // x fragment from LDS
    float xr[16];
    {
      const float4* xl = (const float4*)(x_lds + ibase);
#pragma unroll
      for (int q = 0; q < 4; ++q) {
        const float4 v = xl[q];
        xr[4*q+0] = v.x; xr[4*q+1] = v.y; xr[4*q+2] = v.z; xr[4*q+3] = v.w;
      }
    }
    // partial dots from register-resident A
    float ax = 0.f, ay = 0.f, az = 0.f, aw = 0.f;
#pragma unroll
    for (int k = 0; k < 16; ++k) {
      ax = fmaf(xr[k], ar[4*k+0], ax);
      ay = fmaf(xr[k], ar[4*k+1], ay);
      az = fmaf(xr[k], ar[4*k+2], az);
      aw = fmaf(xr[k], ar[4*k+3], aw);
    }
    // reduce the 8 row-groups within each wave (lane bits 3..5)
#pragma unroll
    for (int m = 8; m <= 32; m <<= 1) {
      ax += __shfl_xor(ax, m);
      ay += __shfl_xor(ay, m);
      az += __shfl_xor(az, m);
      aw += __shfl_xor(aw, m);
    }
    if ((lane >> 3) == 0) {
      ((float4*)red_f)[(wave << 3) + c4] = make_float4(ax, ay, az, aw);
    }

    // prefetch next emission row while we wait at the barrier (no y2 dependency)
    const int o_nxt = obs_lds[t];
    const float4 bb = ((const float4*)(Bt + ((size_t)o_nxt << 12)))[tid];

    __syncthreads();
    const int buf = t & 1;
    if (tid < 32) {   // combine 16 wave partials -> y2 (agent stores)
      float s = 0.f;
      const int cgrp = tid >> 2, ce = tid & 3;
#pragma unroll
      for (int wv = 0; wv < 16; ++wv) {
        s += red_f[(((wv << 3) + cgrp) << 2) + ce];
      }
      agent_st_f32(&y2[(size_t)((buf << 1) + half) * NSTATE + colbase + tid], s);
    }
    grid_bar_fast(flags, w, tid, t + 1);

    // stage next alpha: x = (y_half0 + y_half1) * Bt[obs[t]]
    {
      const unsigned long long* yA =
          (const unsigned long long*)(y2 + (size_t)(buf << 1) * NSTATE);
      const unsigned long long* yB = yA + (NSTATE / 2);
      unsigned long long a0 = agent_ld_u64(&yA[2 * tid]);
      unsigned long long a1 = agent_ld_u64(&yA[2 * tid + 1]);
      unsigned long long b0 = agent_ld_u64(&yB[2 * tid]);
      unsigned long long b1 = agent_ld_u64(&yB[2 * tid + 1]);
      union U { unsigned long long u; float2 f; };
      U ua0, ua1, ub0, ub1;
      ua0.u = a0; ua1.u = a1; ub0.u = b0; ub1.u = b1;
      float4 xx;
      xx.x = (ua0.f.x + ub0.f.x) * bb.x;
      xx.y = (ua0.f.y + ub0.f.y) * bb.y;
      xx.z = (ua1.f.x + ub1.f.x) * bb.z;
      xx.w = (ua1.f.y + ub1.f.y) * bb.w;
      ((float4*)x_lds)[tid] = xx;
    }
    __syncthreads();
  }

  // ---- final sum over alpha (x_lds complete in every wg; wg 0 reports) ----
  if (w == 0) {
    const float4 v = ((const float4*)x_lds)[tid];
    float s = v.x + v.y + v.z + v.w;
#pragma unroll
    for (int m = 1; m <= 32; m <<= 1) s += __shfl_xor(s, m);
    if (lane == 0) fin[wave] = s;
    __syncthreads();
    if (tid == 0) {
      float tot = 0.f;
#pragma unroll
      for (int i = 0; i < 16; ++i) tot += fin[i];
      out[0] = tot;
    }
  }
}

extern "C" void kernel_launch(void* const* d_in, const int* in_sizes, int n_in,
                              void* d_out, int out_size, void* d_ws, size_t ws_size,
                              hipStream_t stream) {
  const float* A   = (const float*)d_in[0];
  const float* B   = (const float*)d_in[1];
  const float* pi  = (const float*)d_in[2];
  const void*  obs = d_in[3];
  float* out = (float*)d_out;
  float* ws  = (float*)d_ws;

  void* args[] = { &A, &B, &pi, &obs, &out, &ws };
  hipLaunchCooperativeKernel((void*)hmm_fwd_kernel, dim3(NWG), dim3(NTHR),
                             args, 0, stream);
}